// Round 1
// baseline (968.189 us; speedup 1.0000x reference)
//
#include <hip/hip_runtime.h>
#include <math.h>

#define NPTS 524288
#define TSZ  524288
#define TMASK (TSZ - 1)

// per-level grid resolutions
__device__ __constant__ float NLf[16] = {
    16.f, 22.f, 30.f, 42.f, 58.f, 80.f, 110.f, 152.f,
    209.f, 288.f, 397.f, 547.f, 754.f, 1039.f, 1432.f, 1974.f
};

// ceil-selector bitmasks over vertex k (bit k set => use ceil on that axis)
// x: k in {1,5,6,7} -> 0xE2 ; y: k in {2,4,6,7} -> 0xD4 ; z: k in {3,4,5,7} -> 0xB8
#define CEILX 0xE2
#define CEILY 0xD4
#define CEILZ 0xB8

__global__ __launch_bounds__(256) void ngp_fused(
    const float* __restrict__ x, const float* __restrict__ d,
    const float* __restrict__ tables,
    const float* __restrict__ w1a, const float* __restrict__ b1a,
    const float* __restrict__ w1b, const float* __restrict__ b1b,
    const float* __restrict__ w2a, const float* __restrict__ b2a,
    const float* __restrict__ w2b, const float* __restrict__ b2b,
    const float* __restrict__ w2c, const float* __restrict__ b2c,
    float* __restrict__ out)
{
    const int i = blockIdx.x * 256 + threadIdx.x;
    if (i >= NPTS) return;

    // xs = x/3 (true division: mask boundary must be bit-exact vs reference)
    const float xs0 = x[3*i+0] / 3.0f;
    const float xs1 = x[3*i+1] / 3.0f;
    const float xs2 = x[3*i+2] / 3.0f;
    const bool mask = (fabsf(xs0) < 0.5f) & (fabsf(xs1) < 0.5f) & (fabsf(xs2) < 0.5f);
    const float xu0 = xs0 + 0.5f, xu1 = xs1 + 0.5f, xu2 = xs2 + 0.5f;

    // ---- hash-grid features: 16 levels x 2 features ----
    float feats[32];
    #pragma unroll
    for (int l = 0; l < 16; ++l) {
        const float n = NLf[l];
        const float p0 = xu0 * n, p1 = xu1 * n, p2 = xu2 * n;
        const float f0 = floorf(p0), f1 = floorf(p1), f2 = floorf(p2);
        const float fr0 = p0 - f0, fr1 = p1 - f1, fr2 = p2 - f2;
        const int vf0 = (int)f0, vf1 = (int)f1, vf2 = (int)f2;
        const int vc0 = (int)ceilf(p0), vc1 = (int)ceilf(p1), vc2 = (int)ceilf(p2);
        const float2* tbl = (const float2*)(tables + (size_t)l * (TSZ * 2));
        float a0 = 0.f, a1 = 0.f;
        #pragma unroll
        for (int k = 0; k < 8; ++k) {
            // int64 hash mod 2^19 == uint32 math & mask (two's complement low bits)
            const unsigned vx = (unsigned)(((CEILX >> k) & 1) ? vc0 : vf0);
            const unsigned vy = (unsigned)(((CEILY >> k) & 1) ? vc1 : vf1);
            const unsigned vz = (unsigned)(((CEILZ >> k) & 1) ? vc2 : vf2);
            const unsigned h = (vx ^ (vy * 2654435761u) ^ (vz * 805459861u)) & TMASK;
            // weight bits use plain binary order (faithful vertex/weight mismatch)
            const float wx = (k & 1)        ? fr0 : 1.0f - fr0;
            const float wy = ((k >> 1) & 1) ? fr1 : 1.0f - fr1;
            const float wz = ((k >> 2) & 1) ? fr2 : 1.0f - fr2;
            const float wgt = wx * wy * wz;
            const float2 t = tbl[h];
            a0 = fmaf(wgt, t.x, a0);
            a1 = fmaf(wgt, t.y, a1);
        }
        feats[2*l]   = a0;
        feats[2*l+1] = a1;
    }

    // ---- MLP1: [32] -> relu -> [64] -> [16] ----
    float h2v[16];
    {
        float h1[64];
        #pragma unroll
        for (int j = 0; j < 64; ++j) h1[j] = b1a[j];
        #pragma unroll
        for (int i2 = 0; i2 < 32; ++i2) {
            const float f = feats[i2];
            #pragma unroll
            for (int j = 0; j < 64; ++j) h1[j] = fmaf(f, w1a[i2*64 + j], h1[j]);
        }
        #pragma unroll
        for (int j = 0; j < 64; ++j) h1[j] = fmaxf(h1[j], 0.f);

        #pragma unroll
        for (int j = 0; j < 16; ++j) h2v[j] = b1b[j];
        #pragma unroll
        for (int i2 = 0; i2 < 64; ++i2) {
            const float f = h1[i2];
            #pragma unroll
            for (int j = 0; j < 16; ++j) h2v[j] = fmaf(f, w1b[i2*16 + j], h2v[j]);
        }
        // no relu on h2v (reference: h = relu(.)@w1b + b1b)
    }

    // ---- z = [h (16), posenc(d) (27)] = 43 ----
    const float d0 = d[3*i+0], d1 = d[3*i+1], d2 = d[3*i+2];
    float z[43];
    #pragma unroll
    for (int j = 0; j < 16; ++j) z[j] = h2v[j];
    z[16] = d0; z[17] = d1; z[18] = d2;
    #pragma unroll
    for (int e = 0; e < 4; ++e) {
        const float m = (float)(1 << e);
        z[19 + 6*e + 0] = sinf(m * d0);
        z[19 + 6*e + 1] = sinf(m * d1);
        z[19 + 6*e + 2] = sinf(m * d2);
        z[19 + 6*e + 3] = cosf(m * d0);
        z[19 + 6*e + 4] = cosf(m * d1);
        z[19 + 6*e + 5] = cosf(m * d2);
    }

    // ---- layer 2a: [43] -> relu[64] ----
    float z1[64];
    #pragma unroll
    for (int j = 0; j < 64; ++j) z1[j] = b2a[j];
    #pragma unroll
    for (int i2 = 0; i2 < 43; ++i2) {
        const float f = z[i2];
        #pragma unroll
        for (int j = 0; j < 64; ++j) z1[j] = fmaf(f, w2a[i2*64 + j], z1[j]);
    }
    #pragma unroll
    for (int j = 0; j < 64; ++j) z1[j] = fmaxf(z1[j], 0.f);

    // ---- layer 2b (relu) fused with 2c, in chunks of 16 outputs ----
    float ca = b2c[0], cb = b2c[1], cc = b2c[2];
    #pragma unroll
    for (int jc = 0; jc < 64; jc += 16) {
        float acc[16];
        #pragma unroll
        for (int jj = 0; jj < 16; ++jj) acc[jj] = b2b[jc + jj];
        #pragma unroll
        for (int i2 = 0; i2 < 64; ++i2) {
            const float f = z1[i2];
            #pragma unroll
            for (int jj = 0; jj < 16; ++jj)
                acc[jj] = fmaf(f, w2b[i2*64 + jc + jj], acc[jj]);
        }
        #pragma unroll
        for (int jj = 0; jj < 16; ++jj) {
            const float v = fmaxf(acc[jj], 0.f);
            ca = fmaf(v, w2c[(jc + jj)*3 + 0], ca);
            cb = fmaf(v, w2c[(jc + jj)*3 + 1], cb);
            cc = fmaf(v, w2c[(jc + jj)*3 + 2], cc);
        }
    }

    // ---- outputs ----
    float r = 1.0f / (1.0f + expf(-ca));
    float g = 1.0f / (1.0f + expf(-cb));
    float b = 1.0f / (1.0f + expf(-cc));
    float sigma;
    if (mask) {
        sigma = expf(h2v[0]);
    } else {
        r = 0.f; g = 0.f; b = 0.f;
        sigma = 0.f;  // exp(-100000) underflows to 0 in f32
    }
    out[3*i + 0] = r;
    out[3*i + 1] = g;
    out[3*i + 2] = b;
    out[3*NPTS + i] = sigma;
}

extern "C" void kernel_launch(void* const* d_in, const int* in_sizes, int n_in,
                              void* d_out, int out_size, void* d_ws, size_t ws_size,
                              hipStream_t stream) {
    const float* x      = (const float*)d_in[0];
    const float* d      = (const float*)d_in[1];
    const float* tables = (const float*)d_in[2];
    const float* w1a    = (const float*)d_in[3];
    const float* b1a    = (const float*)d_in[4];
    const float* w1b    = (const float*)d_in[5];
    const float* b1b    = (const float*)d_in[6];
    const float* w2a    = (const float*)d_in[7];
    const float* b2a    = (const float*)d_in[8];
    const float* w2b    = (const float*)d_in[9];
    const float* b2b    = (const float*)d_in[10];
    const float* w2c    = (const float*)d_in[11];
    const float* b2c    = (const float*)d_in[12];
    float* out = (float*)d_out;

    dim3 grid(NPTS / 256), block(256);
    hipLaunchKernelGGL(ngp_fused, grid, block, 0, stream,
                       x, d, tables, w1a, b1a, w1b, b1b,
                       w2a, b2a, w2b, b2b, w2c, b2c, out);
}